// Round 5
// baseline (136.019 us; speedup 1.0000x reference)
//
#include <hip/hip_runtime.h>
#include <hip/hip_fp16.h>
#include <cstdint>
#include <cmath>

#define B_ 128
#define P_ 8732
#define QU_ 2183        // P_ / 4 exactly
#define M_ 16
#define NT 1024
#define NW 16           // waves per block == M_
#define TAIL_ (QU_ - 2*NT)   // 135: threads with a valid 3rd prior
#define PSTRIDE 9216    // padded bcew row stride in halves (= 64*144, rows 16B-aligned)
#define NFV 144         // halves per lane in K2 (PSTRIDE / 64)
#define NSLOT 16        // mailbox sub-slots per object (lane>>2): 32-bank coverage

// softplus via raw v_exp_f32/v_log_f32 (both ~1 ulp):
// softplus(x) = max(x,0) + ln2 * log2(1 + exp2(-|x|*log2e))
__device__ __forceinline__ float softplusf(float x) {
    float e = __builtin_amdgcn_exp2f(fabsf(x) * -1.44269504f);
    return fmaxf(x, 0.0f) + 0.69314718f * __builtin_amdgcn_logf(1.0f + e);
}

__device__ __forceinline__ float wred_sum_f(float v) {
#pragma unroll
    for (int o = 32; o > 0; o >>= 1) v += __shfl_down(v, o, 64);
    return v;
}
__device__ __forceinline__ int wred_sum_i(int v) {
#pragma unroll
    for (int o = 32; o > 0; o >>= 1) v += __shfl_down(v, o, 64);
    return v;
}

// Phase D for one prior: BCE + (if positive) L1 decode, store bcew.
// Identical float ops / ordering to the verified baseline kernel.
__device__ __forceinline__ void phaseD(
    int r, int p, float bv, int bm, float4 pr,
    float x0, float x1, float x2,
    const float* s_boxes, const int* s_labels,
    const float* __restrict__ plocs,
    unsigned short* __restrict__ bcew,
    int& np, float& cp, float& ls)
{
    bool pos = bv >= 0.5f;
    int lab = pos ? s_labels[bm] : 0;
    float t0 = (lab == 0) ? 1.0f : 0.0f;
    float t1 = (lab == 1 || lab == 3) ? 1.0f : 0.0f;
    float t2 = (lab == 2 || lab == 3) ? 1.0f : 0.0f;
    float bce = (softplusf(x0) - x0*t0) + (softplusf(x1) - x1*t1) + (softplusf(x2) - x2*t2);
    float hb = 0.0f;
    if (pos) {
        np++; cp += bce;
        float4 bb = ((const float4*)s_boxes)[bm];
        float cx = (bb.x + bb.z) * 0.5f, cy = (bb.y + bb.w) * 0.5f;
        float w = bb.z - bb.x, hh = bb.w - bb.y;
        float g0 = (cx - pr.x) / (pr.z * 0.1f);
        float g1 = (cy - pr.y) / (pr.w * 0.1f);
        float g2 = logf(w / pr.z) * 5.0f;
        float g3 = logf(hh / pr.w) * 5.0f;
        float4 pl = ((const float4*)plocs)[(size_t)r * P_ + p];
        ls += fabsf(pl.x - g0) + fabsf(pl.y - g1) + fabsf(pl.z - g2) + fabsf(pl.w - g3);
    } else {
        hb = bce;
    }
    bcew[(size_t)r * PSTRIDE + p] = __half_as_ushort(__float2half(hb));
}

// ============ K1: TRANSPOSED match, 16-slot mailbox argmax. grid = 512. =====
// Each thread owns <=3 priors in registers; inner loop over 16 objects.
// Per-prior argmax over m: register compare (m ascending, strict > = JAX
// first-max). Per-object argmax over p: packed u64 LDS atomicMax
// ((bits(ov)<<32)|(16383-p): lexicographic (ov, lowest-p) - exact first-max)
// into slot (lane>>2): a wave's atomics spread over 16 u64 addresses = all
// 32 banks, max 4-way same-address serialization (R4's wave-uniform slot
// serialized all 64 lanes on one address - that was the 25-30us DS stall).
// Skip when ov==0; init = (0, p0) so all-zero quarters resolve to p0; K2's
// strict-> merge then yields global p=0, matching JAX argmax of all-zeros.
__global__ __launch_bounds__(NT) void mbox_match_kernel(
    const float* __restrict__ plocs,   // (B,P,4)
    const float* __restrict__ pscores, // (B,P,3)
    const float* __restrict__ boxes,   // (B,M,4) xyxy
    const int*   __restrict__ labels,  // (B,M)
    const float* __restrict__ priors,  // (P,4) cxcy
    unsigned short* __restrict__ bcew,
    int2* __restrict__ cand,
    float* __restrict__ pcf, float* __restrict__ plc, int* __restrict__ pnp,
    unsigned int* __restrict__ gz)     // 4 words to zero (g_cnt,g_conf,g_loc,g_np)
{
    __shared__ float s_boxes[M_ * 4];
    __shared__ float s_area[M_];
    __shared__ int   s_labels[M_];
    __shared__ unsigned long long s_obj[M_ * NSLOT];   // [m][slot 0..15]
    __shared__ float s_pf[2 * NW];
    __shared__ int   s_pi[NW];

    const int bk = blockIdx.x;
    const int r  = bk >> 2;
    const int q  = bk & 3;
    const int tid = threadIdx.x;
    const int lane = tid & 63;
    const int wid = tid >> 6;
    const int p0 = q * QU_;

    if (bk == 0 && tid < 4) gz[tid] = 0u;   // zero global accumulators for K2

    // ---- prefetch this thread's priors + scores (overlaps LDS setup)
    const int  pA = p0 + tid;           // always valid (tid < 1024 <= QU_)
    const int  pB = pA + NT;            // always valid (NT+1023 < QU_)
    const bool cok = tid < TAIL_;
    const int  pC = cok ? (pB + NT) : pA;   // clamped, masked later

    float4 prA = ((const float4*)priors)[pA];
    float4 prB = ((const float4*)priors)[pB];
    float4 prC = ((const float4*)priors)[pC];

    const float* scA = pscores + ((size_t)r * P_ + pA) * 3;
    const float* scB = pscores + ((size_t)r * P_ + pB) * 3;
    const float* scC = pscores + ((size_t)r * P_ + pC) * 3;
    float xA0 = scA[0], xA1 = scA[1], xA2 = scA[2];
    float xB0 = scB[0], xB1 = scB[1], xB2 = scB[2];
    float xC0 = scC[0], xC1 = scC[1], xC2 = scC[2];

    if (tid < M_ * 4) s_boxes[tid] = boxes[r * M_ * 4 + tid];
    if (tid >= 64 && tid < 64 + M_) s_labels[tid - 64] = labels[r * M_ + (tid - 64)];
    if (tid >= 128 && tid < 128 + M_ * NSLOT)
        s_obj[tid - 128] = (unsigned long long)(unsigned)(16383 - p0);  // (ov=0, p=p0)
    __syncthreads();
    if (tid < M_) {
        float x0 = s_boxes[tid*4+0], y0 = s_boxes[tid*4+1];
        float x1 = s_boxes[tid*4+2], y1 = s_boxes[tid*4+3];
        s_area[tid] = (x1 - x0) * (y1 - y0);
    }
    __syncthreads();

    // prior corners + areas (computed once, reused for all 16 objects)
    float aX0 = prA.x - prA.z*0.5f, aY0 = prA.y - prA.w*0.5f;
    float aX1 = prA.x + prA.z*0.5f, aY1 = prA.y + prA.w*0.5f;
    float aAr = prA.z * prA.w;
    float bX0 = prB.x - prB.z*0.5f, bY0 = prB.y - prB.w*0.5f;
    float bX1 = prB.x + prB.z*0.5f, bY1 = prB.y + prB.w*0.5f;
    float bAr = prB.z * prB.w;
    float cX0 = prC.x - prC.z*0.5f, cY0 = prC.y - prC.w*0.5f;
    float cX1 = prC.x + prC.z*0.5f, cY1 = prC.y + prC.w*0.5f;
    float cAr = prC.z * prC.w;

    // per-prior best (over m): strict >, m ascending -> first-max; init m=0
    float bvA = -1.0f, bvB = -1.0f, bvC = -1.0f;
    int   bmA = 0,     bmB = 0,     bmC = 0;
    const int slot = lane >> 2;    // per-quad slot: 16 addrs/wave = 32 banks

#pragma unroll
    for (int m = 0; m < M_; ++m) {
        float4 bb = ((const float4*)s_boxes)[m];   // broadcast read
        float mar = s_area[m];

        float ltx, lty, rbx, rby, wx, wy, inter;

        ltx = fmaxf(bb.x, aX0); lty = fmaxf(bb.y, aY0);
        rbx = fminf(bb.z, aX1); rby = fminf(bb.w, aY1);
        wx = fmaxf(rbx - ltx, 0.0f); wy = fmaxf(rby - lty, 0.0f);
        inter = wx * wy;
        float ovA = inter * __builtin_amdgcn_rcpf(mar + aAr - inter);

        ltx = fmaxf(bb.x, bX0); lty = fmaxf(bb.y, bY0);
        rbx = fminf(bb.z, bX1); rby = fminf(bb.w, bY1);
        wx = fmaxf(rbx - ltx, 0.0f); wy = fmaxf(rby - lty, 0.0f);
        inter = wx * wy;
        float ovB = inter * __builtin_amdgcn_rcpf(mar + bAr - inter);

        float ovC = -1.0f;
        if (cok) {     // waves 3..15 skip entirely (execz)
            ltx = fmaxf(bb.x, cX0); lty = fmaxf(bb.y, cY0);
            rbx = fminf(bb.z, cX1); rby = fminf(bb.w, cY1);
            wx = fmaxf(rbx - ltx, 0.0f); wy = fmaxf(rby - lty, 0.0f);
            inter = wx * wy;
            ovC = inter * __builtin_amdgcn_rcpf(mar + cAr - inter);
        }

        if (ovA > bvA) { bvA = ovA; bmA = m; }
        if (ovB > bvB) { bvB = ovB; bmB = m; }
        if (ovC > bvC) { bvC = ovC; bmC = m; }

        // per-object best over this thread's 3 priors (earliest p on ties)
        float v = ovA; int idx = pA;
        if (ovB > v) { v = ovB; idx = pB; }
        if (ovC > v) { v = ovC; idx = pC; }
        if (v > 0.0f) {
            unsigned long long pk =
                ((unsigned long long)__float_as_uint(v) << 32)
                | (unsigned long long)(unsigned)(16383 - idx);
            atomicMax(&s_obj[(m << 4) | slot], pk);
        }
    }

    // ---- fused phase D on register-resident per-prior results
    int np = 0; float cp = 0.0f, ls = 0.0f;
    phaseD(r, pA, bvA, bmA, prA, xA0, xA1, xA2, s_boxes, s_labels,
           plocs, bcew, np, cp, ls);
    phaseD(r, pB, bvB, bmB, prB, xB0, xB1, xB2, s_boxes, s_labels,
           plocs, bcew, np, cp, ls);
    if (cok)
        phaseD(r, pC, bvC, bmC, prC, xC0, xC1, xC2, s_boxes, s_labels,
               plocs, bcew, np, cp, ls);

    // ---- reduce quarter partials
    cp = wred_sum_f(cp);
    ls = wred_sum_f(ls);
    np = wred_sum_i(np);
    if (lane == 0) { s_pf[wid] = cp; s_pf[NW + wid] = ls; s_pi[wid] = np; }
    __syncthreads();   // all mailbox atomics + s_pf complete here

    if (tid < M_) {
        unsigned long long bb = s_obj[tid << 4];
#pragma unroll
        for (int s = 1; s < NSLOT; ++s) {
            unsigned long long b = s_obj[(tid << 4) | s];
            if (b > bb) bb = b;     // exact: pack order == (ov, lowest-p) order
        }
        float v = __uint_as_float((unsigned)(bb >> 32));
        int idx = 16383 - (int)(bb & 0xFFFFFFFFull);
        cand[bk * M_ + tid] = make_int2(__float_as_int(v), idx);
    }
    if (tid == 0) {
        float c2 = 0.0f, l2 = 0.0f; int n2 = 0;
#pragma unroll
        for (int w = 0; w < NW; ++w) { c2 += s_pf[w]; l2 += s_pf[NW + w]; n2 += s_pi[w]; }
        pcf[bk] = c2; plc[bk] = l2; pnp[bk] = n2;
    }
}

// ============ K2: one WAVE per row: fixup + register-resident bisection. ====
// grid = 128 x 64 threads. Single wave => no barriers; counting via
// ballot+popcount (wave-uniform scalar result, no cross-lane shuffle chain).
// Row's 9216 padded fp16 patterns live in 144 VGPRs/lane (static indices).
// Multiset identical to the old 9x1024 layout => identical bisection
// trajectory. Fixup recomputes (oldpos, oldobj) at the <=16 candidate
// priors bit-identically from priors+boxes.
__global__ __launch_bounds__(64) void mbox_loss_kernel(
    const float* __restrict__ plocs,
    const float* __restrict__ pscores,
    const float* __restrict__ boxes,
    const int*   __restrict__ labels,
    const float* __restrict__ priors,
    const unsigned short* __restrict__ bcew,
    const int2* __restrict__ cand,
    const float* __restrict__ pcf, const float* __restrict__ plc,
    const int* __restrict__ pnp,
    float* __restrict__ out,
    unsigned int* __restrict__ g_cnt,
    float* __restrict__ g_conf, float* __restrict__ g_loc, int* __restrict__ g_np)
{
    __shared__ unsigned short s_fv[PSTRIDE];   // 18432 B
    __shared__ float s_boxes[M_ * 4];
    __shared__ int   s_labels[M_];
    __shared__ int   s_po[M_];

    const int r = blockIdx.x;
    const int lane = threadIdx.x;   // 0..63, one wave

    // ---- stage padded bcew row -> LDS (18 x uint4 per lane)
    {
        const uint4* src = (const uint4*)(bcew + (size_t)r * PSTRIDE);
        uint4* dst = (uint4*)s_fv;
#pragma unroll
        for (int j = 0; j < 18; ++j)
            dst[j * 64 + lane] = src[j * 64 + lane];
    }
    s_boxes[lane] = boxes[r * 64 + lane];            // exactly 64 floats
    if (lane < M_) s_labels[lane] = labels[r * M_ + lane];
    if (lane < M_) {
        int2 c = cand[(r * 4) * M_ + lane];
        float v = __int_as_float(c.x); int idx = c.y;
#pragma unroll
        for (int qq = 1; qq < 4; ++qq) {
            int2 c2 = cand[(r * 4 + qq) * M_ + lane];
            float v2 = __int_as_float(c2.x);
            if (v2 > v) { v = v2; idx = c2.y; }   // strict >: earliest quarter wins
        }
        s_po[lane] = idx;
    }
    __syncthreads();

    // ---- zero pad region (garbage from poisoned ws) + forced-positive priors
    for (int p = P_ + lane; p < PSTRIDE; p += 64) s_fv[p] = 0;
    if (lane < M_) s_fv[s_po[lane]] = 0;   // every s_po entry ends positive

    // ---- fixup: lane m owns object m; "last m wins" => owner iff no m'>m
    //      maps to the same prior. (overlaps the LDS zero writes)
    float dcp = 0.0f, dls = 0.0f; int dnp = 0;
    if (lane < M_) {
        const int m = lane;
        const int idx = s_po[m];
        bool owner = true;
        for (int m2 = m + 1; m2 < M_; ++m2)
            if (s_po[m2] == idx) owner = false;
        if (owner) {
            // recompute per-prior argmax at idx: identical exprs/order as K1
            float4 pr = ((const float4*)priors)[idx];
            float pX0 = pr.x - pr.z*0.5f, pY0 = pr.y - pr.w*0.5f;
            float pX1 = pr.x + pr.z*0.5f, pY1 = pr.y + pr.w*0.5f;
            float pAr = pr.z * pr.w;
            float obv = -1.0f; int obm = 0;
#pragma unroll
            for (int mm = 0; mm < M_; ++mm) {
                float4 bb = ((const float4*)s_boxes)[mm];
                float mar = (bb.z - bb.x) * (bb.w - bb.y);
                float ltx = fmaxf(bb.x, pX0), lty = fmaxf(bb.y, pY0);
                float rbx = fminf(bb.z, pX1), rby = fminf(bb.w, pY1);
                float wx = fmaxf(rbx - ltx, 0.0f), wy = fmaxf(rby - lty, 0.0f);
                float inter = wx * wy;
                float ov = inter * __builtin_amdgcn_rcpf(mar + pAr - inter);
                if (ov > obv) { obv = ov; obm = mm; }
            }
            bool oldpos = obv >= 0.5f;
            int  oldobj = obm;

            const float* sc = pscores + ((size_t)r * P_ + idx) * 3;
            float x0 = sc[0], x1 = sc[1], x2 = sc[2];
            float S = softplusf(x0) + softplusf(x1) + softplusf(x2);
            float4 pl = ((const float4*)plocs)[(size_t)r * P_ + idx];
            {
                int lab = s_labels[m];
                float t0 = (lab == 0) ? 1.0f : 0.0f;
                float t1 = (lab == 1 || lab == 3) ? 1.0f : 0.0f;
                float t2 = (lab == 2 || lab == 3) ? 1.0f : 0.0f;
                dcp += S - (x0*t0 + x1*t1 + x2*t2);
                float bx0 = s_boxes[m*4+0], by0 = s_boxes[m*4+1];
                float bx1 = s_boxes[m*4+2], by1 = s_boxes[m*4+3];
                float cx = (bx0+bx1)*0.5f, cy = (by0+by1)*0.5f;
                float w = bx1-bx0, hh = by1-by0;
                float g0 = (cx - pr.x) / (pr.z * 0.1f);
                float g1 = (cy - pr.y) / (pr.w * 0.1f);
                float g2 = logf(w / pr.z) * 5.0f;
                float g3 = logf(hh / pr.w) * 5.0f;
                dls += fabsf(pl.x-g0)+fabsf(pl.y-g1)+fabsf(pl.z-g2)+fabsf(pl.w-g3);
                dnp += 1;
            }
            if (oldpos) {
                int lab = s_labels[oldobj];
                float t0 = (lab == 0) ? 1.0f : 0.0f;
                float t1 = (lab == 1 || lab == 3) ? 1.0f : 0.0f;
                float t2 = (lab == 2 || lab == 3) ? 1.0f : 0.0f;
                dcp -= S - (x0*t0 + x1*t1 + x2*t2);
                float bx0 = s_boxes[oldobj*4+0], by0 = s_boxes[oldobj*4+1];
                float bx1 = s_boxes[oldobj*4+2], by1 = s_boxes[oldobj*4+3];
                float cx = (bx0+bx1)*0.5f, cy = (by0+by1)*0.5f;
                float w = bx1-bx0, hh = by1-by0;
                float g0 = (cx - pr.x) / (pr.z * 0.1f);
                float g1 = (cy - pr.y) / (pr.w * 0.1f);
                float g2 = logf(w / pr.z) * 5.0f;
                float g3 = logf(hh / pr.w) * 5.0f;
                dls -= fabsf(pl.x-g0)+fabsf(pl.y-g1)+fabsf(pl.z-g2)+fabsf(pl.w-g3);
                dnp -= 1;
            }
        }
    }
    dcp = wred_sum_f(dcp);
    dls = wred_sum_f(dls);
    dnp = wred_sum_i(dnp);
    float cp = 0.0f, lsx = 0.0f; int np = 0;
    if (lane == 0) {
        cp = dcp; lsx = dls; np = dnp;
#pragma unroll
        for (int qq = 0; qq < 4; ++qq) {
            cp  += pcf[r * 4 + qq];
            lsx += plc[r * 4 + qq];
            np  += pnp[r * 4 + qq];
        }
    }
    const int npos_row = __shfl(np, 0, 64);

    __syncthreads();   // s_fv zeroing complete before reads

    // ---- LDS -> 144 registers (static indices only)
    int fv[NFV];
#pragma unroll
    for (int j = 0; j < 18; ++j) {
        uint4 d = ((const uint4*)s_fv)[j * 64 + lane];
        fv[j*8+0] = (int)(d.x & 0xFFFFu); fv[j*8+1] = (int)(d.x >> 16);
        fv[j*8+2] = (int)(d.y & 0xFFFFu); fv[j*8+3] = (int)(d.y >> 16);
        fv[j*8+4] = (int)(d.z & 0xFFFFu); fv[j*8+5] = (int)(d.z >> 16);
        fv[j*8+6] = (int)(d.w & 0xFFFFu); fv[j*8+7] = (int)(d.w >> 16);
    }

    // ---- exact top-k: 15-step bisection; counts via ballot+popcount
    //      (wave-uniform, no cross-lane shuffle chains, no barriers)
    int k = 3 * npos_row;
    if (k > P_) k = P_;
    float hard_sum = 0.0f;
    if (k > 0) {
        int lo = -1, hi = 0x7C00;   // invariant: cnt(lo)>=k, cnt(hi)<k
        for (int it = 0; it < 15; ++it) {
            int mid = (lo + hi) >> 1;
            int c = 0;
#pragma unroll
            for (int i = 0; i < NFV; ++i)
                c += (int)__popcll(__ballot(fv[i] > mid));
            if (c < k) hi = mid; else lo = mid;   // c uniform on all lanes
        }
        int tb = hi;                               // k-th largest fp16 pattern
        float tval = __half2float(__ushort_as_half((unsigned short)tb));
        float lsum = 0.0f; int lcnt = 0;
#pragma unroll
        for (int i = 0; i < NFV; ++i) {
            if (fv[i] > tb) {
                lsum += __half2float(__ushort_as_half((unsigned short)fv[i]));
                lcnt++;
            }
        }
        lsum = wred_sum_f(lsum);
        lcnt = wred_sum_i(lcnt);
        if (lane == 0) hard_sum = lsum + (float)(k - lcnt) * tval;
    }

    // ---- finalize
    if (lane == 0) {
        float conf_row = cp + hard_sum;
        float loc_row  = lsx;
        out[3 + r] = (float)npos_row;
        atomicAdd(g_conf, conf_row);
        atomicAdd(g_loc,  loc_row);
        atomicAdd(g_np,   npos_row);
        __threadfence();
        unsigned int done = atomicAdd(g_cnt, 1u);
        if (done == B_ - 1) {
            float ct = atomicAdd(g_conf, 0.0f);
            float lt = atomicAdd(g_loc,  0.0f);
            int   npt_i = atomicAdd(g_np, 0);
            float npt = (float)npt_i;
            float conf_loss = ct / (1e-10f + npt);
            float loc_loss = (npt_i > 0) ? lt / (4.0f * fmaxf(npt, 1.0f)) : 0.0f;
            out[0] = conf_loss + loc_loss;   // ALPHA = 1
            out[1] = conf_loss;
            out[2] = loc_loss;
        }
    }
}

extern "C" void kernel_launch(void* const* d_in, const int* in_sizes, int n_in,
                              void* d_out, int out_size, void* d_ws, size_t ws_size,
                              hipStream_t stream) {
    const float* plocs   = (const float*)d_in[0];
    const float* pscores = (const float*)d_in[1];
    const float* boxes   = (const float*)d_in[2];
    const int*   labels  = (const int*)  d_in[3];
    const float* priors  = (const float*)d_in[4];
    float* out = (float*)d_out;

    // ws layout (~2.4 MB total):
    //   [0,16)        g_cnt, g_conf, g_loc, g_np
    //   [64, +2K)     pcf float[512]
    //   [2112, +2K)   plc float[512]
    //   [4160, +2K)   pnp int[512]
    //   [8192, +64K)  cand int2[512*16]              -> ends 73728
    //   [73728, +2359296) bcew fp16 (stride PSTRIDE=9216, rows 16B-aligned)
    char* ws = (char*)d_ws;
    unsigned int* g_cnt  = (unsigned int*)ws;
    float*        g_conf = (float*)(ws + 4);
    float*        g_loc  = (float*)(ws + 8);
    int*          g_np   = (int*)(ws + 12);
    float*        pcf    = (float*)(ws + 64);
    float*        plc    = (float*)(ws + 2112);
    int*          pnp    = (int*)(ws + 4160);
    int2*         cand   = (int2*)(ws + 8192);
    unsigned short* bcew = (unsigned short*)(ws + 73728);

    mbox_match_kernel<<<4 * B_, NT, 0, stream>>>(plocs, pscores, boxes, labels, priors,
                                                 bcew, cand, pcf, plc, pnp,
                                                 (unsigned int*)ws);
    mbox_loss_kernel<<<B_, 64, 0, stream>>>(plocs, pscores, boxes, labels, priors,
                                            bcew, cand, pcf, plc, pnp,
                                            out, g_cnt, g_conf, g_loc, g_np);
}

// Round 6
// 115.937 us; speedup vs baseline: 1.1732x; 1.1732x over previous
//
#include <hip/hip_runtime.h>
#include <hip/hip_fp16.h>
#include <cstdint>
#include <cmath>

#define B_ 128
#define P_ 8732
#define QU_ 2183        // P_ / 4 exactly
#define M_ 16
#define NT 1024
#define NW 16           // waves per block == M_ (K1)
#define TAIL_ (QU_ - 2*NT)   // 135: threads with a valid 3rd prior
#define PSTRIDE 9216    // padded bcew row stride in halves (= 64*144, rows 16B-aligned)
#define NSLOT 16        // K1 mailbox sub-slots per object (lane>>2): 32-bank coverage
#define K2NT 512        // K2 threads (8 waves)
#define K2NW 8
#define NU9 9           // uints per K2 thread (9*512 = 4608 = PSTRIDE/2)
#define NFV2 18         // fp16 patterns per K2 thread

// softplus via raw v_exp_f32/v_log_f32 (both ~1 ulp):
// softplus(x) = max(x,0) + ln2 * log2(1 + exp2(-|x|*log2e))
__device__ __forceinline__ float softplusf(float x) {
    float e = __builtin_amdgcn_exp2f(fabsf(x) * -1.44269504f);
    return fmaxf(x, 0.0f) + 0.69314718f * __builtin_amdgcn_logf(1.0f + e);
}

__device__ __forceinline__ float wred_sum_f(float v) {
#pragma unroll
    for (int o = 32; o > 0; o >>= 1) v += __shfl_down(v, o, 64);
    return v;
}
__device__ __forceinline__ int wred_sum_i(int v) {
#pragma unroll
    for (int o = 32; o > 0; o >>= 1) v += __shfl_down(v, o, 64);
    return v;
}

// Phase D for one prior: BCE + (if positive) L1 decode, store bcew.
// Identical float ops / ordering to the verified baseline kernel.
__device__ __forceinline__ void phaseD(
    int r, int p, float bv, int bm, float4 pr,
    float x0, float x1, float x2,
    const float* s_boxes, const int* s_labels,
    const float* __restrict__ plocs,
    unsigned short* __restrict__ bcew,
    int& np, float& cp, float& ls)
{
    bool pos = bv >= 0.5f;
    int lab = pos ? s_labels[bm] : 0;
    float t0 = (lab == 0) ? 1.0f : 0.0f;
    float t1 = (lab == 1 || lab == 3) ? 1.0f : 0.0f;
    float t2 = (lab == 2 || lab == 3) ? 1.0f : 0.0f;
    float bce = (softplusf(x0) - x0*t0) + (softplusf(x1) - x1*t1) + (softplusf(x2) - x2*t2);
    float hb = 0.0f;
    if (pos) {
        np++; cp += bce;
        float4 bb = ((const float4*)s_boxes)[bm];
        float cx = (bb.x + bb.z) * 0.5f, cy = (bb.y + bb.w) * 0.5f;
        float w = bb.z - bb.x, hh = bb.w - bb.y;
        float g0 = (cx - pr.x) / (pr.z * 0.1f);
        float g1 = (cy - pr.y) / (pr.w * 0.1f);
        float g2 = logf(w / pr.z) * 5.0f;
        float g3 = logf(hh / pr.w) * 5.0f;
        float4 pl = ((const float4*)plocs)[(size_t)r * P_ + p];
        ls += fabsf(pl.x - g0) + fabsf(pl.y - g1) + fabsf(pl.z - g2) + fabsf(pl.w - g3);
    } else {
        hb = bce;
    }
    bcew[(size_t)r * PSTRIDE + p] = __half_as_ushort(__float2half(hb));
}

// ============ K1: TRANSPOSED match, 16-slot mailbox argmax. grid = 512. =====
// (unchanged from the verified Round-5 kernel; ~25us measured-by-decomposition)
__global__ __launch_bounds__(NT) void mbox_match_kernel(
    const float* __restrict__ plocs,   // (B,P,4)
    const float* __restrict__ pscores, // (B,P,3)
    const float* __restrict__ boxes,   // (B,M,4) xyxy
    const int*   __restrict__ labels,  // (B,M)
    const float* __restrict__ priors,  // (P,4) cxcy
    unsigned short* __restrict__ bcew,
    int2* __restrict__ cand,
    float* __restrict__ pcf, float* __restrict__ plc, int* __restrict__ pnp,
    unsigned int* __restrict__ gz)     // 4 words to zero (g_cnt,g_conf,g_loc,g_np)
{
    __shared__ float s_boxes[M_ * 4];
    __shared__ float s_area[M_];
    __shared__ int   s_labels[M_];
    __shared__ unsigned long long s_obj[M_ * NSLOT];   // [m][slot 0..15]
    __shared__ float s_pf[2 * NW];
    __shared__ int   s_pi[NW];

    const int bk = blockIdx.x;
    const int r  = bk >> 2;
    const int q  = bk & 3;
    const int tid = threadIdx.x;
    const int lane = tid & 63;
    const int wid = tid >> 6;
    const int p0 = q * QU_;

    if (bk == 0 && tid < 4) gz[tid] = 0u;   // zero global accumulators for K2

    // ---- prefetch this thread's priors + scores (overlaps LDS setup)
    const int  pA = p0 + tid;           // always valid (tid < 1024 <= QU_)
    const int  pB = pA + NT;            // always valid (NT+1023 < QU_)
    const bool cok = tid < TAIL_;
    const int  pC = cok ? (pB + NT) : pA;   // clamped, masked later

    float4 prA = ((const float4*)priors)[pA];
    float4 prB = ((const float4*)priors)[pB];
    float4 prC = ((const float4*)priors)[pC];

    const float* scA = pscores + ((size_t)r * P_ + pA) * 3;
    const float* scB = pscores + ((size_t)r * P_ + pB) * 3;
    const float* scC = pscores + ((size_t)r * P_ + pC) * 3;
    float xA0 = scA[0], xA1 = scA[1], xA2 = scA[2];
    float xB0 = scB[0], xB1 = scB[1], xB2 = scB[2];
    float xC0 = scC[0], xC1 = scC[1], xC2 = scC[2];

    if (tid < M_ * 4) s_boxes[tid] = boxes[r * M_ * 4 + tid];
    if (tid >= 64 && tid < 64 + M_) s_labels[tid - 64] = labels[r * M_ + (tid - 64)];
    if (tid >= 128 && tid < 128 + M_ * NSLOT)
        s_obj[tid - 128] = (unsigned long long)(unsigned)(16383 - p0);  // (ov=0, p=p0)
    __syncthreads();
    if (tid < M_) {
        float x0 = s_boxes[tid*4+0], y0 = s_boxes[tid*4+1];
        float x1 = s_boxes[tid*4+2], y1 = s_boxes[tid*4+3];
        s_area[tid] = (x1 - x0) * (y1 - y0);
    }
    __syncthreads();

    // prior corners + areas (computed once, reused for all 16 objects)
    float aX0 = prA.x - prA.z*0.5f, aY0 = prA.y - prA.w*0.5f;
    float aX1 = prA.x + prA.z*0.5f, aY1 = prA.y + prA.w*0.5f;
    float aAr = prA.z * prA.w;
    float bX0 = prB.x - prB.z*0.5f, bY0 = prB.y - prB.w*0.5f;
    float bX1 = prB.x + prB.z*0.5f, bY1 = prB.y + prB.w*0.5f;
    float bAr = prB.z * prB.w;
    float cX0 = prC.x - prC.z*0.5f, cY0 = prC.y - prC.w*0.5f;
    float cX1 = prC.x + prC.z*0.5f, cY1 = prC.y + prC.w*0.5f;
    float cAr = prC.z * prC.w;

    // per-prior best (over m): strict >, m ascending -> first-max; init m=0
    float bvA = -1.0f, bvB = -1.0f, bvC = -1.0f;
    int   bmA = 0,     bmB = 0,     bmC = 0;
    const int slot = lane >> 2;    // per-quad slot: 16 addrs/wave = 32 banks

#pragma unroll
    for (int m = 0; m < M_; ++m) {
        float4 bb = ((const float4*)s_boxes)[m];   // broadcast read
        float mar = s_area[m];

        float ltx, lty, rbx, rby, wx, wy, inter;

        ltx = fmaxf(bb.x, aX0); lty = fmaxf(bb.y, aY0);
        rbx = fminf(bb.z, aX1); rby = fminf(bb.w, aY1);
        wx = fmaxf(rbx - ltx, 0.0f); wy = fmaxf(rby - lty, 0.0f);
        inter = wx * wy;
        float ovA = inter * __builtin_amdgcn_rcpf(mar + aAr - inter);

        ltx = fmaxf(bb.x, bX0); lty = fmaxf(bb.y, bY0);
        rbx = fminf(bb.z, bX1); rby = fminf(bb.w, bY1);
        wx = fmaxf(rbx - ltx, 0.0f); wy = fmaxf(rby - lty, 0.0f);
        inter = wx * wy;
        float ovB = inter * __builtin_amdgcn_rcpf(mar + bAr - inter);

        float ovC = -1.0f;
        if (cok) {     // waves 3..15 skip entirely (execz)
            ltx = fmaxf(bb.x, cX0); lty = fmaxf(bb.y, cY0);
            rbx = fminf(bb.z, cX1); rby = fminf(bb.w, cY1);
            wx = fmaxf(rbx - ltx, 0.0f); wy = fmaxf(rby - lty, 0.0f);
            inter = wx * wy;
            ovC = inter * __builtin_amdgcn_rcpf(mar + cAr - inter);
        }

        if (ovA > bvA) { bvA = ovA; bmA = m; }
        if (ovB > bvB) { bvB = ovB; bmB = m; }
        if (ovC > bvC) { bvC = ovC; bmC = m; }

        // per-object best over this thread's 3 priors (earliest p on ties)
        float v = ovA; int idx = pA;
        if (ovB > v) { v = ovB; idx = pB; }
        if (ovC > v) { v = ovC; idx = pC; }
        if (v > 0.0f) {
            unsigned long long pk =
                ((unsigned long long)__float_as_uint(v) << 32)
                | (unsigned long long)(unsigned)(16383 - idx);
            atomicMax(&s_obj[(m << 4) | slot], pk);
        }
    }

    // ---- fused phase D on register-resident per-prior results
    int np = 0; float cp = 0.0f, ls = 0.0f;
    phaseD(r, pA, bvA, bmA, prA, xA0, xA1, xA2, s_boxes, s_labels,
           plocs, bcew, np, cp, ls);
    phaseD(r, pB, bvB, bmB, prB, xB0, xB1, xB2, s_boxes, s_labels,
           plocs, bcew, np, cp, ls);
    if (cok)
        phaseD(r, pC, bvC, bmC, prC, xC0, xC1, xC2, s_boxes, s_labels,
               plocs, bcew, np, cp, ls);

    // ---- reduce quarter partials
    cp = wred_sum_f(cp);
    ls = wred_sum_f(ls);
    np = wred_sum_i(np);
    if (lane == 0) { s_pf[wid] = cp; s_pf[NW + wid] = ls; s_pi[wid] = np; }
    __syncthreads();   // all mailbox atomics + s_pf complete here

    if (tid < M_) {
        unsigned long long bb = s_obj[tid << 4];
#pragma unroll
        for (int s = 1; s < NSLOT; ++s) {
            unsigned long long b = s_obj[(tid << 4) | s];
            if (b > bb) bb = b;     // exact: pack order == (ov, lowest-p) order
        }
        float v = __uint_as_float((unsigned)(bb >> 32));
        int idx = 16383 - (int)(bb & 0xFFFFFFFFull);
        cand[bk * M_ + tid] = make_int2(__float_as_int(v), idx);
    }
    if (tid == 0) {
        float c2 = 0.0f, l2 = 0.0f; int n2 = 0;
#pragma unroll
        for (int w = 0; w < NW; ++w) { c2 += s_pf[w]; l2 += s_pf[NW + w]; n2 += s_pi[w]; }
        pcf[bk] = c2; plc[bk] = l2; pnp[bk] = n2;
    }
}

// ============ K2: 8 waves per row, register-resident bisection. grid = 128. =
// R5's 1-wave K2 was latency-bound (43us at 1.5% VALUBusy: serial 144-link
// count chains, 1 wave/CU). Now: 512 threads, 18 patterns/thread in regs
// (9 coalesced uint loads, pad synthesized as 0 -> no LDS row buffer).
// Per round: 18 independent cmp+add/lane + 1 wave-reduce + 8-wave LDS
// combine (double-buffered, 1 barrier). Forced-positive clearing in-register
// via static-index mask. Bisection multiset/trajectory identical to R5.
__global__ __launch_bounds__(K2NT) void mbox_loss_kernel(
    const float* __restrict__ plocs,
    const float* __restrict__ pscores,
    const float* __restrict__ boxes,
    const int*   __restrict__ labels,
    const float* __restrict__ priors,
    const unsigned short* __restrict__ bcew,
    const int2* __restrict__ cand,
    const float* __restrict__ pcf, const float* __restrict__ plc,
    const int* __restrict__ pnp,
    float* __restrict__ out,
    unsigned int* __restrict__ g_cnt,
    float* __restrict__ g_conf, float* __restrict__ g_loc, int* __restrict__ g_np)
{
    __shared__ float s_boxes[M_ * 4];
    __shared__ int   s_labels[M_];
    __shared__ int   s_po[M_];
    __shared__ float s_pf[2 * K2NW];
    __shared__ int   s_pi[K2NW];
    __shared__ int   s_cnt2[2][K2NW];
    __shared__ float s_scal[2];
    __shared__ int   s_npos;

    const int r = blockIdx.x;
    const int tid = threadIdx.x;
    const int lane = tid & 63;
    const int wid = tid >> 6;

    // ---- 18 fp16 patterns per thread, register-resident.
    // pattern p lives in thread (p>>1)%512 slot 2*((p>>1)/512)+(p&1).
    // pad region [P_,PSTRIDE) synthesized as 0 (uints >= P_/2 not loaded).
    int fv[NFV2];
    {
        const unsigned int* src = (const unsigned int*)(bcew + (size_t)r * PSTRIDE);
#pragma unroll
        for (int j = 0; j < NU9; ++j) {
            int u = j * K2NT + tid;
            unsigned int d = 0u;
            if (u < (P_ / 2)) d = src[u];
            fv[2*j]   = (int)(d & 0xFFFFu);
            fv[2*j+1] = (int)(d >> 16);
        }
    }

    if (tid < M_ * 4) s_boxes[tid] = boxes[r * M_ * 4 + tid];
    if (tid >= 64 && tid < 64 + M_) s_labels[tid - 64] = labels[r * M_ + (tid - 64)];
    if (tid >= 128 && tid < 128 + M_) {
        int m = tid - 128;
        int2 c = cand[(r * 4) * M_ + m];
        float v = __int_as_float(c.x); int idx = c.y;
#pragma unroll
        for (int qq = 1; qq < 4; ++qq) {
            int2 c2 = cand[(r * 4 + qq) * M_ + m];
            float v2 = __int_as_float(c2.x);
            if (v2 > v) { v = v2; idx = c2.y; }   // strict >: earliest quarter wins
        }
        s_po[m] = idx;
    }
    __syncthreads();

    // ---- clear forced-positive priors in this thread's registers.
    // p = j*1024 + 2*tid + h  ->  rel = p - 2*tid = j*1024 + h:
    // valid iff 0 <= rel < PSTRIDE and bits 1..9 of rel are zero.
    {
        unsigned int mask = 0u;
#pragma unroll
        for (int jj = 0; jj < M_; ++jj) {
            int rel = s_po[jj] - 2 * tid;
            if (rel >= 0 && rel < PSTRIDE && (rel & 1022) == 0)
                mask |= 1u << (((rel >> 10) << 1) | (rel & 1));
        }
        if (mask) {
#pragma unroll
            for (int i = 0; i < NFV2; ++i)
                if (mask & (1u << i)) fv[i] = 0;
        }
    }

    // ---- fixup on wave 0: lane m owns object m; "last m wins" => owner iff
    //      no m'>m maps to the same prior. Recomputes (oldpos, oldobj)
    //      bit-identically from priors+boxes.
    if (wid == 0) {
        float dcp = 0.0f, dls = 0.0f; int dnp = 0;
        if (lane < M_) {
            const int m = lane;
            const int idx = s_po[m];
            bool owner = true;
            for (int m2 = m + 1; m2 < M_; ++m2)
                if (s_po[m2] == idx) owner = false;
            if (owner) {
                float4 pr = ((const float4*)priors)[idx];
                float pX0 = pr.x - pr.z*0.5f, pY0 = pr.y - pr.w*0.5f;
                float pX1 = pr.x + pr.z*0.5f, pY1 = pr.y + pr.w*0.5f;
                float pAr = pr.z * pr.w;
                float obv = -1.0f; int obm = 0;
#pragma unroll
                for (int mm = 0; mm < M_; ++mm) {
                    float4 bb = ((const float4*)s_boxes)[mm];
                    float mar = (bb.z - bb.x) * (bb.w - bb.y);
                    float ltx = fmaxf(bb.x, pX0), lty = fmaxf(bb.y, pY0);
                    float rbx = fminf(bb.z, pX1), rby = fminf(bb.w, pY1);
                    float wx = fmaxf(rbx - ltx, 0.0f), wy = fmaxf(rby - lty, 0.0f);
                    float inter = wx * wy;
                    float ov = inter * __builtin_amdgcn_rcpf(mar + pAr - inter);
                    if (ov > obv) { obv = ov; obm = mm; }
                }
                bool oldpos = obv >= 0.5f;
                int  oldobj = obm;

                const float* sc = pscores + ((size_t)r * P_ + idx) * 3;
                float x0 = sc[0], x1 = sc[1], x2 = sc[2];
                float S = softplusf(x0) + softplusf(x1) + softplusf(x2);
                float4 pl = ((const float4*)plocs)[(size_t)r * P_ + idx];
                {
                    int lab = s_labels[m];
                    float t0 = (lab == 0) ? 1.0f : 0.0f;
                    float t1 = (lab == 1 || lab == 3) ? 1.0f : 0.0f;
                    float t2 = (lab == 2 || lab == 3) ? 1.0f : 0.0f;
                    dcp += S - (x0*t0 + x1*t1 + x2*t2);
                    float bx0 = s_boxes[m*4+0], by0 = s_boxes[m*4+1];
                    float bx1 = s_boxes[m*4+2], by1 = s_boxes[m*4+3];
                    float cx = (bx0+bx1)*0.5f, cy = (by0+by1)*0.5f;
                    float w = bx1-bx0, hh = by1-by0;
                    float g0 = (cx - pr.x) / (pr.z * 0.1f);
                    float g1 = (cy - pr.y) / (pr.w * 0.1f);
                    float g2 = logf(w / pr.z) * 5.0f;
                    float g3 = logf(hh / pr.w) * 5.0f;
                    dls += fabsf(pl.x-g0)+fabsf(pl.y-g1)+fabsf(pl.z-g2)+fabsf(pl.w-g3);
                    dnp += 1;
                }
                if (oldpos) {
                    int lab = s_labels[oldobj];
                    float t0 = (lab == 0) ? 1.0f : 0.0f;
                    float t1 = (lab == 1 || lab == 3) ? 1.0f : 0.0f;
                    float t2 = (lab == 2 || lab == 3) ? 1.0f : 0.0f;
                    dcp -= S - (x0*t0 + x1*t1 + x2*t2);
                    float bx0 = s_boxes[oldobj*4+0], by0 = s_boxes[oldobj*4+1];
                    float bx1 = s_boxes[oldobj*4+2], by1 = s_boxes[oldobj*4+3];
                    float cx = (bx0+bx1)*0.5f, cy = (by0+by1)*0.5f;
                    float w = bx1-bx0, hh = by1-by0;
                    float g0 = (cx - pr.x) / (pr.z * 0.1f);
                    float g1 = (cy - pr.y) / (pr.w * 0.1f);
                    float g2 = logf(w / pr.z) * 5.0f;
                    float g3 = logf(hh / pr.w) * 5.0f;
                    dls -= fabsf(pl.x-g0)+fabsf(pl.y-g1)+fabsf(pl.z-g2)+fabsf(pl.w-g3);
                    dnp -= 1;
                }
            }
        }
        dcp = wred_sum_f(dcp);
        dls = wred_sum_f(dls);
        dnp = wred_sum_i(dnp);
        if (lane == 0) {
            float cp = dcp, lsx = dls; int np = dnp;
#pragma unroll
            for (int qq = 0; qq < 4; ++qq) {
                cp  += pcf[r * 4 + qq];
                lsx += plc[r * 4 + qq];
                np  += pnp[r * 4 + qq];
            }
            s_scal[0] = cp; s_scal[1] = lsx; s_npos = np;
        }
    }
    __syncthreads();
    const int npos_row = s_npos;

    // ---- exact top-k: 15-step bisection; per-lane counts + wave reduce +
    //      8-wave LDS combine (double-buffered, 1 barrier/round)
    int k = 3 * npos_row;
    if (k > P_) k = P_;
    float hard_sum = 0.0f;
    if (k > 0) {
        int lo = -1, hi = 0x7C00;   // invariant: cnt(lo)>=k, cnt(hi)<k
        for (int it = 0; it < 15; ++it) {
            int mid = (lo + hi) >> 1;
            int c = 0;
#pragma unroll
            for (int i = 0; i < NFV2; ++i) c += (fv[i] > mid) ? 1 : 0;
            c = wred_sum_i(c);
            if (lane == 0) s_cnt2[it & 1][wid] = c;
            __syncthreads();
            int cnt = 0;
#pragma unroll
            for (int w = 0; w < K2NW; ++w) cnt += s_cnt2[it & 1][w];
            if (cnt < k) hi = mid; else lo = mid;   // uniform on all threads
        }
        int tb = hi;                               // k-th largest fp16 pattern
        float tval = __half2float(__ushort_as_half((unsigned short)tb));
        float lsum = 0.0f; int lcnt = 0;
#pragma unroll
        for (int i = 0; i < NFV2; ++i) {
            if (fv[i] > tb) {
                lsum += __half2float(__ushort_as_half((unsigned short)fv[i]));
                lcnt++;
            }
        }
        lsum = wred_sum_f(lsum);
        lcnt = wred_sum_i(lcnt);
        if (lane == 0) { s_pf[wid] = lsum; s_pi[wid] = lcnt; }
        __syncthreads();
        if (tid == 0) {
            float sv = 0.0f; int sc2 = 0;
#pragma unroll
            for (int w = 0; w < K2NW; ++w) { sv += s_pf[w]; sc2 += s_pi[w]; }
            hard_sum = sv + (float)(k - sc2) * tval;
        }
    }

    // ---- finalize
    if (tid == 0) {
        float conf_row = s_scal[0] + hard_sum;
        float loc_row  = s_scal[1];
        out[3 + r] = (float)npos_row;
        atomicAdd(g_conf, conf_row);
        atomicAdd(g_loc,  loc_row);
        atomicAdd(g_np,   npos_row);
        __threadfence();
        unsigned int done = atomicAdd(g_cnt, 1u);
        if (done == B_ - 1) {
            float ct = atomicAdd(g_conf, 0.0f);
            float lt = atomicAdd(g_loc,  0.0f);
            int   npt_i = atomicAdd(g_np, 0);
            float npt = (float)npt_i;
            float conf_loss = ct / (1e-10f + npt);
            float loc_loss = (npt_i > 0) ? lt / (4.0f * fmaxf(npt, 1.0f)) : 0.0f;
            out[0] = conf_loss + loc_loss;   // ALPHA = 1
            out[1] = conf_loss;
            out[2] = loc_loss;
        }
    }
}

extern "C" void kernel_launch(void* const* d_in, const int* in_sizes, int n_in,
                              void* d_out, int out_size, void* d_ws, size_t ws_size,
                              hipStream_t stream) {
    const float* plocs   = (const float*)d_in[0];
    const float* pscores = (const float*)d_in[1];
    const float* boxes   = (const float*)d_in[2];
    const int*   labels  = (const int*)  d_in[3];
    const float* priors  = (const float*)d_in[4];
    float* out = (float*)d_out;

    // ws layout (~2.4 MB total):
    //   [0,16)        g_cnt, g_conf, g_loc, g_np
    //   [64, +2K)     pcf float[512]
    //   [2112, +2K)   plc float[512]
    //   [4160, +2K)   pnp int[512]
    //   [8192, +64K)  cand int2[512*16]              -> ends 73728
    //   [73728, +2359296) bcew fp16 (stride PSTRIDE=9216, rows 16B-aligned)
    char* ws = (char*)d_ws;
    unsigned int* g_cnt  = (unsigned int*)ws;
    float*        g_conf = (float*)(ws + 4);
    float*        g_loc  = (float*)(ws + 8);
    int*          g_np   = (int*)(ws + 12);
    float*        pcf    = (float*)(ws + 64);
    float*        plc    = (float*)(ws + 2112);
    int*          pnp    = (int*)(ws + 4160);
    int2*         cand   = (int2*)(ws + 8192);
    unsigned short* bcew = (unsigned short*)(ws + 73728);

    mbox_match_kernel<<<4 * B_, NT, 0, stream>>>(plocs, pscores, boxes, labels, priors,
                                                 bcew, cand, pcf, plc, pnp,
                                                 (unsigned int*)ws);
    mbox_loss_kernel<<<B_, K2NT, 0, stream>>>(plocs, pscores, boxes, labels, priors,
                                              bcew, cand, pcf, plc, pnp,
                                              out, g_cnt, g_conf, g_loc, g_np);
}

// Round 7
// 114.338 us; speedup vs baseline: 1.1896x; 1.0140x over previous
//
#include <hip/hip_runtime.h>
#include <hip/hip_fp16.h>
#include <cstdint>
#include <cmath>

#define B_ 128
#define P_ 8732
#define QU_ 2183        // P_ / 4 exactly
#define M_ 16
#define NT 1024
#define NW 16           // waves per block == M_ (K1)
#define TAIL_ (QU_ - 2*NT)   // 135: threads with a valid 3rd prior
#define PSTRIDE 9216    // padded bcew row stride in halves (= 64*144, rows 16B-aligned)
#define NSLOT 16        // K1 mailbox sub-slots per object (lane>>2): 32-bank coverage
#define K2NT 512        // K2 threads (8 waves)
#define K2NW 8
#define NU9 9           // uints per K2 thread (9*512 = 4608 = PSTRIDE/2)
#define NFV2 18         // fp16 patterns per K2 thread

// softplus via raw v_exp_f32/v_log_f32 (both ~1 ulp):
// softplus(x) = max(x,0) + ln2 * log2(1 + exp2(-|x|*log2e))
__device__ __forceinline__ float softplusf(float x) {
    float e = __builtin_amdgcn_exp2f(fabsf(x) * -1.44269504f);
    return fmaxf(x, 0.0f) + 0.69314718f * __builtin_amdgcn_logf(1.0f + e);
}

__device__ __forceinline__ float wred_sum_f(float v) {
#pragma unroll
    for (int o = 32; o > 0; o >>= 1) v += __shfl_down(v, o, 64);
    return v;
}
__device__ __forceinline__ int wred_sum_i(int v) {
#pragma unroll
    for (int o = 32; o > 0; o >>= 1) v += __shfl_down(v, o, 64);
    return v;
}

// Phase D for one prior: BCE + (if positive) L1 decode, store bcew.
// Identical float ops / ordering to the verified baseline kernel.
__device__ __forceinline__ void phaseD(
    int r, int p, float bv, int bm, float4 pr,
    float x0, float x1, float x2,
    const float* s_boxes, const int* s_labels,
    const float* __restrict__ plocs,
    unsigned short* __restrict__ bcew,
    int& np, float& cp, float& ls)
{
    bool pos = bv >= 0.5f;
    int lab = pos ? s_labels[bm] : 0;
    float t0 = (lab == 0) ? 1.0f : 0.0f;
    float t1 = (lab == 1 || lab == 3) ? 1.0f : 0.0f;
    float t2 = (lab == 2 || lab == 3) ? 1.0f : 0.0f;
    float bce = (softplusf(x0) - x0*t0) + (softplusf(x1) - x1*t1) + (softplusf(x2) - x2*t2);
    float hb = 0.0f;
    if (pos) {
        np++; cp += bce;
        float4 bb = ((const float4*)s_boxes)[bm];
        float cx = (bb.x + bb.z) * 0.5f, cy = (bb.y + bb.w) * 0.5f;
        float w = bb.z - bb.x, hh = bb.w - bb.y;
        float g0 = (cx - pr.x) / (pr.z * 0.1f);
        float g1 = (cy - pr.y) / (pr.w * 0.1f);
        float g2 = logf(w / pr.z) * 5.0f;
        float g3 = logf(hh / pr.w) * 5.0f;
        float4 pl = ((const float4*)plocs)[(size_t)r * P_ + p];
        ls += fabsf(pl.x - g0) + fabsf(pl.y - g1) + fabsf(pl.z - g2) + fabsf(pl.w - g3);
    } else {
        hb = bce;
    }
    bcew[(size_t)r * PSTRIDE + p] = __half_as_ushort(__float2half(hb));
}

// ============ K1: TRANSPOSED match, 16-slot mailbox argmax. grid = 512. =====
// Structure identical to verified Round-6 kernel. ONLY change: launch_bounds
// 2nd arg = 4 waves/EU. Without it the backend's occupancy heuristic targets
// 8 waves/EU -> 64-VGPR cap -> allocator squeezed the ~58-reg live set to 56
// via remat of the 15 corner values inside the 16x-unrolled m-loop + score
// spills (the ~4x dynamic-instr bloat seen as 51% VALUBusy at 44us in R2).
// 4 waves/EU -> 128-VGPR budget, 16 waves/CU resident (still 4/SIMD).
__global__ __launch_bounds__(NT, 4) void mbox_match_kernel(
    const float* __restrict__ plocs,   // (B,P,4)
    const float* __restrict__ pscores, // (B,P,3)
    const float* __restrict__ boxes,   // (B,M,4) xyxy
    const int*   __restrict__ labels,  // (B,M)
    const float* __restrict__ priors,  // (P,4) cxcy
    unsigned short* __restrict__ bcew,
    int2* __restrict__ cand,
    float* __restrict__ pcf, float* __restrict__ plc, int* __restrict__ pnp,
    unsigned int* __restrict__ gz)     // 4 words to zero (g_cnt,g_conf,g_loc,g_np)
{
    __shared__ float s_boxes[M_ * 4];
    __shared__ float s_area[M_];
    __shared__ int   s_labels[M_];
    __shared__ unsigned long long s_obj[M_ * NSLOT];   // [m][slot 0..15]
    __shared__ float s_pf[2 * NW];
    __shared__ int   s_pi[NW];

    const int bk = blockIdx.x;
    const int r  = bk >> 2;
    const int q  = bk & 3;
    const int tid = threadIdx.x;
    const int lane = tid & 63;
    const int wid = tid >> 6;
    const int p0 = q * QU_;

    if (bk == 0 && tid < 4) gz[tid] = 0u;   // zero global accumulators for K2

    // ---- prefetch this thread's priors + scores (overlaps LDS setup)
    const int  pA = p0 + tid;           // always valid (tid < 1024 <= QU_)
    const int  pB = pA + NT;            // always valid (NT+1023 < QU_)
    const bool cok = tid < TAIL_;
    const int  pC = cok ? (pB + NT) : pA;   // clamped, masked later

    float4 prA = ((const float4*)priors)[pA];
    float4 prB = ((const float4*)priors)[pB];
    float4 prC = ((const float4*)priors)[pC];

    const float* scA = pscores + ((size_t)r * P_ + pA) * 3;
    const float* scB = pscores + ((size_t)r * P_ + pB) * 3;
    const float* scC = pscores + ((size_t)r * P_ + pC) * 3;
    float xA0 = scA[0], xA1 = scA[1], xA2 = scA[2];
    float xB0 = scB[0], xB1 = scB[1], xB2 = scB[2];
    float xC0 = scC[0], xC1 = scC[1], xC2 = scC[2];

    if (tid < M_ * 4) s_boxes[tid] = boxes[r * M_ * 4 + tid];
    if (tid >= 64 && tid < 64 + M_) s_labels[tid - 64] = labels[r * M_ + (tid - 64)];
    if (tid >= 128 && tid < 128 + M_ * NSLOT)
        s_obj[tid - 128] = (unsigned long long)(unsigned)(16383 - p0);  // (ov=0, p=p0)
    __syncthreads();
    if (tid < M_) {
        float x0 = s_boxes[tid*4+0], y0 = s_boxes[tid*4+1];
        float x1 = s_boxes[tid*4+2], y1 = s_boxes[tid*4+3];
        s_area[tid] = (x1 - x0) * (y1 - y0);
    }
    __syncthreads();

    // prior corners + areas (computed once, reused for all 16 objects)
    float aX0 = prA.x - prA.z*0.5f, aY0 = prA.y - prA.w*0.5f;
    float aX1 = prA.x + prA.z*0.5f, aY1 = prA.y + prA.w*0.5f;
    float aAr = prA.z * prA.w;
    float bX0 = prB.x - prB.z*0.5f, bY0 = prB.y - prB.w*0.5f;
    float bX1 = prB.x + prB.z*0.5f, bY1 = prB.y + prB.w*0.5f;
    float bAr = prB.z * prB.w;
    float cX0 = prC.x - prC.z*0.5f, cY0 = prC.y - prC.w*0.5f;
    float cX1 = prC.x + prC.z*0.5f, cY1 = prC.y + prC.w*0.5f;
    float cAr = prC.z * prC.w;

    // per-prior best (over m): strict >, m ascending -> first-max; init m=0
    float bvA = -1.0f, bvB = -1.0f, bvC = -1.0f;
    int   bmA = 0,     bmB = 0,     bmC = 0;
    const int slot = lane >> 2;    // per-quad slot: 16 addrs/wave = 32 banks

#pragma unroll
    for (int m = 0; m < M_; ++m) {
        float4 bb = ((const float4*)s_boxes)[m];   // broadcast read
        float mar = s_area[m];

        float ltx, lty, rbx, rby, wx, wy, inter;

        ltx = fmaxf(bb.x, aX0); lty = fmaxf(bb.y, aY0);
        rbx = fminf(bb.z, aX1); rby = fminf(bb.w, aY1);
        wx = fmaxf(rbx - ltx, 0.0f); wy = fmaxf(rby - lty, 0.0f);
        inter = wx * wy;
        float ovA = inter * __builtin_amdgcn_rcpf(mar + aAr - inter);

        ltx = fmaxf(bb.x, bX0); lty = fmaxf(bb.y, bY0);
        rbx = fminf(bb.z, bX1); rby = fminf(bb.w, bY1);
        wx = fmaxf(rbx - ltx, 0.0f); wy = fmaxf(rby - lty, 0.0f);
        inter = wx * wy;
        float ovB = inter * __builtin_amdgcn_rcpf(mar + bAr - inter);

        float ovC = -1.0f;
        if (cok) {     // uniform skip for waves 3..15 (divergent only in wave 2)
            ltx = fmaxf(bb.x, cX0); lty = fmaxf(bb.y, cY0);
            rbx = fminf(bb.z, cX1); rby = fminf(bb.w, cY1);
            wx = fmaxf(rbx - ltx, 0.0f); wy = fmaxf(rby - lty, 0.0f);
            inter = wx * wy;
            ovC = inter * __builtin_amdgcn_rcpf(mar + cAr - inter);
        }

        if (ovA > bvA) { bvA = ovA; bmA = m; }
        if (ovB > bvB) { bvB = ovB; bmB = m; }
        if (ovC > bvC) { bvC = ovC; bmC = m; }

        // per-object best over this thread's 3 priors (earliest p on ties)
        float v = ovA; int idx = pA;
        if (ovB > v) { v = ovB; idx = pB; }
        if (ovC > v) { v = ovC; idx = pC; }
        if (v > 0.0f) {
            unsigned long long pk =
                ((unsigned long long)__float_as_uint(v) << 32)
                | (unsigned long long)(unsigned)(16383 - idx);
            atomicMax(&s_obj[(m << 4) | slot], pk);
        }
    }

    // ---- fused phase D on register-resident per-prior results
    int np = 0; float cp = 0.0f, ls = 0.0f;
    phaseD(r, pA, bvA, bmA, prA, xA0, xA1, xA2, s_boxes, s_labels,
           plocs, bcew, np, cp, ls);
    phaseD(r, pB, bvB, bmB, prB, xB0, xB1, xB2, s_boxes, s_labels,
           plocs, bcew, np, cp, ls);
    if (cok)
        phaseD(r, pC, bvC, bmC, prC, xC0, xC1, xC2, s_boxes, s_labels,
               plocs, bcew, np, cp, ls);

    // ---- reduce quarter partials
    cp = wred_sum_f(cp);
    ls = wred_sum_f(ls);
    np = wred_sum_i(np);
    if (lane == 0) { s_pf[wid] = cp; s_pf[NW + wid] = ls; s_pi[wid] = np; }
    __syncthreads();   // all mailbox atomics + s_pf complete here

    if (tid < M_) {
        unsigned long long bb = s_obj[tid << 4];
#pragma unroll
        for (int s = 1; s < NSLOT; ++s) {
            unsigned long long b = s_obj[(tid << 4) | s];
            if (b > bb) bb = b;     // exact: pack order == (ov, lowest-p) order
        }
        float v = __uint_as_float((unsigned)(bb >> 32));
        int idx = 16383 - (int)(bb & 0xFFFFFFFFull);
        cand[bk * M_ + tid] = make_int2(__float_as_int(v), idx);
    }
    if (tid == 0) {
        float c2 = 0.0f, l2 = 0.0f; int n2 = 0;
#pragma unroll
        for (int w = 0; w < NW; ++w) { c2 += s_pf[w]; l2 += s_pf[NW + w]; n2 += s_pi[w]; }
        pcf[bk] = c2; plc[bk] = l2; pnp[bk] = n2;
    }
}

// ============ K2: 8 waves per row, register-resident bisection. grid = 128. =
// Structure identical to verified Round-6 kernel. ONLY change: launch_bounds
// 2nd arg = 2 waves/EU. grid (128) < CUs (256) -> at most 1 block/CU anyway,
// so the declaration costs zero occupancy and lifts the VGPR budget to 256
// (fv[18] + staging temps were at risk of spilling under the heuristic 64-cap).
__global__ __launch_bounds__(K2NT, 2) void mbox_loss_kernel(
    const float* __restrict__ plocs,
    const float* __restrict__ pscores,
    const float* __restrict__ boxes,
    const int*   __restrict__ labels,
    const float* __restrict__ priors,
    const unsigned short* __restrict__ bcew,
    const int2* __restrict__ cand,
    const float* __restrict__ pcf, const float* __restrict__ plc,
    const int* __restrict__ pnp,
    float* __restrict__ out,
    unsigned int* __restrict__ g_cnt,
    float* __restrict__ g_conf, float* __restrict__ g_loc, int* __restrict__ g_np)
{
    __shared__ float s_boxes[M_ * 4];
    __shared__ int   s_labels[M_];
    __shared__ int   s_po[M_];
    __shared__ float s_pf[2 * K2NW];
    __shared__ int   s_pi[K2NW];
    __shared__ int   s_cnt2[2][K2NW];
    __shared__ float s_scal[2];
    __shared__ int   s_npos;

    const int r = blockIdx.x;
    const int tid = threadIdx.x;
    const int lane = tid & 63;
    const int wid = tid >> 6;

    // ---- 18 fp16 patterns per thread, register-resident.
    // pattern p lives in thread (p>>1)%512 slot 2*((p>>1)/512)+(p&1).
    // pad region [P_,PSTRIDE) synthesized as 0 (uints >= P_/2 not loaded).
    int fv[NFV2];
    {
        const unsigned int* src = (const unsigned int*)(bcew + (size_t)r * PSTRIDE);
#pragma unroll
        for (int j = 0; j < NU9; ++j) {
            int u = j * K2NT + tid;
            unsigned int d = 0u;
            if (u < (P_ / 2)) d = src[u];
            fv[2*j]   = (int)(d & 0xFFFFu);
            fv[2*j+1] = (int)(d >> 16);
        }
    }

    if (tid < M_ * 4) s_boxes[tid] = boxes[r * M_ * 4 + tid];
    if (tid >= 64 && tid < 64 + M_) s_labels[tid - 64] = labels[r * M_ + (tid - 64)];
    if (tid >= 128 && tid < 128 + M_) {
        int m = tid - 128;
        int2 c = cand[(r * 4) * M_ + m];
        float v = __int_as_float(c.x); int idx = c.y;
#pragma unroll
        for (int qq = 1; qq < 4; ++qq) {
            int2 c2 = cand[(r * 4 + qq) * M_ + m];
            float v2 = __int_as_float(c2.x);
            if (v2 > v) { v = v2; idx = c2.y; }   // strict >: earliest quarter wins
        }
        s_po[m] = idx;
    }
    __syncthreads();

    // ---- clear forced-positive priors in this thread's registers.
    // p = j*1024 + 2*tid + h  ->  rel = p - 2*tid = j*1024 + h:
    // valid iff 0 <= rel < PSTRIDE and bits 1..9 of rel are zero.
    {
        unsigned int mask = 0u;
#pragma unroll
        for (int jj = 0; jj < M_; ++jj) {
            int rel = s_po[jj] - 2 * tid;
            if (rel >= 0 && rel < PSTRIDE && (rel & 1022) == 0)
                mask |= 1u << (((rel >> 10) << 1) | (rel & 1));
        }
        if (mask) {
#pragma unroll
            for (int i = 0; i < NFV2; ++i)
                if (mask & (1u << i)) fv[i] = 0;
        }
    }

    // ---- fixup on wave 0: lane m owns object m; "last m wins" => owner iff
    //      no m'>m maps to the same prior. Recomputes (oldpos, oldobj)
    //      bit-identically from priors+boxes.
    if (wid == 0) {
        float dcp = 0.0f, dls = 0.0f; int dnp = 0;
        if (lane < M_) {
            const int m = lane;
            const int idx = s_po[m];
            bool owner = true;
            for (int m2 = m + 1; m2 < M_; ++m2)
                if (s_po[m2] == idx) owner = false;
            if (owner) {
                float4 pr = ((const float4*)priors)[idx];
                float pX0 = pr.x - pr.z*0.5f, pY0 = pr.y - pr.w*0.5f;
                float pX1 = pr.x + pr.z*0.5f, pY1 = pr.y + pr.w*0.5f;
                float pAr = pr.z * pr.w;
                float obv = -1.0f; int obm = 0;
#pragma unroll
                for (int mm = 0; mm < M_; ++mm) {
                    float4 bb = ((const float4*)s_boxes)[mm];
                    float mar = (bb.z - bb.x) * (bb.w - bb.y);
                    float ltx = fmaxf(bb.x, pX0), lty = fmaxf(bb.y, pY0);
                    float rbx = fminf(bb.z, pX1), rby = fminf(bb.w, pY1);
                    float wx = fmaxf(rbx - ltx, 0.0f), wy = fmaxf(rby - lty, 0.0f);
                    float inter = wx * wy;
                    float ov = inter * __builtin_amdgcn_rcpf(mar + pAr - inter);
                    if (ov > obv) { obv = ov; obm = mm; }
                }
                bool oldpos = obv >= 0.5f;
                int  oldobj = obm;

                const float* sc = pscores + ((size_t)r * P_ + idx) * 3;
                float x0 = sc[0], x1 = sc[1], x2 = sc[2];
                float S = softplusf(x0) + softplusf(x1) + softplusf(x2);
                float4 pl = ((const float4*)plocs)[(size_t)r * P_ + idx];
                {
                    int lab = s_labels[m];
                    float t0 = (lab == 0) ? 1.0f : 0.0f;
                    float t1 = (lab == 1 || lab == 3) ? 1.0f : 0.0f;
                    float t2 = (lab == 2 || lab == 3) ? 1.0f : 0.0f;
                    dcp += S - (x0*t0 + x1*t1 + x2*t2);
                    float bx0 = s_boxes[m*4+0], by0 = s_boxes[m*4+1];
                    float bx1 = s_boxes[m*4+2], by1 = s_boxes[m*4+3];
                    float cx = (bx0+bx1)*0.5f, cy = (by0+by1)*0.5f;
                    float w = bx1-bx0, hh = by1-by0;
                    float g0 = (cx - pr.x) / (pr.z * 0.1f);
                    float g1 = (cy - pr.y) / (pr.w * 0.1f);
                    float g2 = logf(w / pr.z) * 5.0f;
                    float g3 = logf(hh / pr.w) * 5.0f;
                    dls += fabsf(pl.x-g0)+fabsf(pl.y-g1)+fabsf(pl.z-g2)+fabsf(pl.w-g3);
                    dnp += 1;
                }
                if (oldpos) {
                    int lab = s_labels[oldobj];
                    float t0 = (lab == 0) ? 1.0f : 0.0f;
                    float t1 = (lab == 1 || lab == 3) ? 1.0f : 0.0f;
                    float t2 = (lab == 2 || lab == 3) ? 1.0f : 0.0f;
                    dcp -= S - (x0*t0 + x1*t1 + x2*t2);
                    float bx0 = s_boxes[oldobj*4+0], by0 = s_boxes[oldobj*4+1];
                    float bx1 = s_boxes[oldobj*4+2], by1 = s_boxes[oldobj*4+3];
                    float cx = (bx0+bx1)*0.5f, cy = (by0+by1)*0.5f;
                    float w = bx1-bx0, hh = by1-by0;
                    float g0 = (cx - pr.x) / (pr.z * 0.1f);
                    float g1 = (cy - pr.y) / (pr.w * 0.1f);
                    float g2 = logf(w / pr.z) * 5.0f;
                    float g3 = logf(hh / pr.w) * 5.0f;
                    dls -= fabsf(pl.x-g0)+fabsf(pl.y-g1)+fabsf(pl.z-g2)+fabsf(pl.w-g3);
                    dnp -= 1;
                }
            }
        }
        dcp = wred_sum_f(dcp);
        dls = wred_sum_f(dls);
        dnp = wred_sum_i(dnp);
        if (lane == 0) {
            float cp = dcp, lsx = dls; int np = dnp;
#pragma unroll
            for (int qq = 0; qq < 4; ++qq) {
                cp  += pcf[r * 4 + qq];
                lsx += plc[r * 4 + qq];
                np  += pnp[r * 4 + qq];
            }
            s_scal[0] = cp; s_scal[1] = lsx; s_npos = np;
        }
    }
    __syncthreads();
    const int npos_row = s_npos;

    // ---- exact top-k: 15-step bisection; per-lane counts + wave reduce +
    //      8-wave LDS combine (double-buffered, 1 barrier/round)
    int k = 3 * npos_row;
    if (k > P_) k = P_;
    float hard_sum = 0.0f;
    if (k > 0) {
        int lo = -1, hi = 0x7C00;   // invariant: cnt(lo)>=k, cnt(hi)<k
        for (int it = 0; it < 15; ++it) {
            int mid = (lo + hi) >> 1;
            int c = 0;
#pragma unroll
            for (int i = 0; i < NFV2; ++i) c += (fv[i] > mid) ? 1 : 0;
            c = wred_sum_i(c);
            if (lane == 0) s_cnt2[it & 1][wid] = c;
            __syncthreads();
            int cnt = 0;
#pragma unroll
            for (int w = 0; w < K2NW; ++w) cnt += s_cnt2[it & 1][w];
            if (cnt < k) hi = mid; else lo = mid;   // uniform on all threads
        }
        int tb = hi;                               // k-th largest fp16 pattern
        float tval = __half2float(__ushort_as_half((unsigned short)tb));
        float lsum = 0.0f; int lcnt = 0;
#pragma unroll
        for (int i = 0; i < NFV2; ++i) {
            if (fv[i] > tb) {
                lsum += __half2float(__ushort_as_half((unsigned short)fv[i]));
                lcnt++;
            }
        }
        lsum = wred_sum_f(lsum);
        lcnt = wred_sum_i(lcnt);
        if (lane == 0) { s_pf[wid] = lsum; s_pi[wid] = lcnt; }
        __syncthreads();
        if (tid == 0) {
            float sv = 0.0f; int sc2 = 0;
#pragma unroll
            for (int w = 0; w < K2NW; ++w) { sv += s_pf[w]; sc2 += s_pi[w]; }
            hard_sum = sv + (float)(k - sc2) * tval;
        }
    }

    // ---- finalize
    if (tid == 0) {
        float conf_row = s_scal[0] + hard_sum;
        float loc_row  = s_scal[1];
        out[3 + r] = (float)npos_row;
        atomicAdd(g_conf, conf_row);
        atomicAdd(g_loc,  loc_row);
        atomicAdd(g_np,   npos_row);
        __threadfence();
        unsigned int done = atomicAdd(g_cnt, 1u);
        if (done == B_ - 1) {
            float ct = atomicAdd(g_conf, 0.0f);
            float lt = atomicAdd(g_loc,  0.0f);
            int   npt_i = atomicAdd(g_np, 0);
            float npt = (float)npt_i;
            float conf_loss = ct / (1e-10f + npt);
            float loc_loss = (npt_i > 0) ? lt / (4.0f * fmaxf(npt, 1.0f)) : 0.0f;
            out[0] = conf_loss + loc_loss;   // ALPHA = 1
            out[1] = conf_loss;
            out[2] = loc_loss;
        }
    }
}

extern "C" void kernel_launch(void* const* d_in, const int* in_sizes, int n_in,
                              void* d_out, int out_size, void* d_ws, size_t ws_size,
                              hipStream_t stream) {
    const float* plocs   = (const float*)d_in[0];
    const float* pscores = (const float*)d_in[1];
    const float* boxes   = (const float*)d_in[2];
    const int*   labels  = (const int*)  d_in[3];
    const float* priors  = (const float*)d_in[4];
    float* out = (float*)d_out;

    // ws layout (~2.4 MB total):
    //   [0,16)        g_cnt, g_conf, g_loc, g_np
    //   [64, +2K)     pcf float[512]
    //   [2112, +2K)   plc float[512]
    //   [4160, +2K)   pnp int[512]
    //   [8192, +64K)  cand int2[512*16]              -> ends 73728
    //   [73728, +2359296) bcew fp16 (stride PSTRIDE=9216, rows 16B-aligned)
    char* ws = (char*)d_ws;
    unsigned int* g_cnt  = (unsigned int*)ws;
    float*        g_conf = (float*)(ws + 4);
    float*        g_loc  = (float*)(ws + 8);
    int*          g_np   = (int*)(ws + 12);
    float*        pcf    = (float*)(ws + 64);
    float*        plc    = (float*)(ws + 2112);
    int*          pnp    = (int*)(ws + 4160);
    int2*         cand   = (int2*)(ws + 8192);
    unsigned short* bcew = (unsigned short*)(ws + 73728);

    mbox_match_kernel<<<4 * B_, NT, 0, stream>>>(plocs, pscores, boxes, labels, priors,
                                                 bcew, cand, pcf, plc, pnp,
                                                 (unsigned int*)ws);
    mbox_loss_kernel<<<B_, K2NT, 0, stream>>>(plocs, pscores, boxes, labels, priors,
                                              bcew, cand, pcf, plc, pnp,
                                              out, g_cnt, g_conf, g_loc, g_np);
}